// Round 1
// baseline (87.637 us; speedup 1.0000x reference)
//
#include <hip/hip_runtime.h>
#include <math.h>

#define T_LEN 8192
#define EPSF  1e-6f

typedef __attribute__((ext_vector_type(8))) short short8;
typedef __attribute__((ext_vector_type(4))) float float4v;

// ---------------------------------------------------------------------------
// Single fused kernel. One block = (batch b, 256-row t-strip), 1024 blocks,
// 256 threads, __launch_bounds__(256,4): exactly 4 blocks/CU, ONE dispatch
// round, no tail.
//
// Phase 0:   stage raw shapelets (16 KB float4) -> Sraw; x window (320 f) -> xs.
// Phase 1:   threads 0-63: serial two-pass znorm + bf16 hi/lo split per
//            shapelet (bit-identical arithmetic to prior rounds), written at
//            permuted B row c = (p&3)*16 + (p>>2). Threads 64-255: window
//            stats for rows 0..191; threads 64-127 additionally rows 192..255.
// Phase 1.5: NEW — pre-pack the 320 window floats into bf16 hi/lo PAIRED
//            dwords (xpack[0..159] = hi, xpack[160..319] = lo), aliased into
//            Sraw's storage (dead after phase 1). One v_perm_b32 per dword.
//            Element math identical to the old per-thread A-pack.
// Phase 2:   B fragments -> registers (reused across FOUR 64-row units);
//            A fragments now come from xpack via ds_read + v_alignbyte_b32
//            (odd-short Hankel offsets handled by the byte-align unit instead
//            of ~400 VALU ops/thread of redundant bit surgery);
//            3-MFMA bf16 hi/lo GEMM; epilogue folds window znorm + exp,
//            direct float4 stores. Rows t<32 / t>8160 are the zero padding.
// ---------------------------------------------------------------------------
__global__ __launch_bounds__(256, 4) void shapelet_fused(
        const float* __restrict__ x,
        const float* __restrict__ sh,
        float* __restrict__ out) {
    __shared__ float Sraw[64][65];             // 16.25 KB prep staging; dwords
                                               // 0..319 reused as xpack later
    __shared__ unsigned short Bhi[64][72];     // 9 KB, 144 B rows (16B-aligned)
    __shared__ unsigned short Blo[64][72];     // 9 KB
    __shared__ __align__(16) float xs[320];    // x[t0-32 .. t0+287]
    __shared__ float lmu[256], linv[256], lw2[256];   // 3 KB
    __shared__ __align__(16) float lsum[64];   // logical-p order
    __shared__ __align__(16) float ls2[64];

    const int tid  = threadIdx.x;
    const int lane = tid & 63;
    const int wave = tid >> 6;
    const int n    = lane & 15;
    const int quad = lane >> 4;

    const int super = blockIdx.x & 31;         // 32 strips of 256 rows
    const int b     = blockIdx.x >> 5;         // 32 batches
    const int t0    = super << 8;

    // ---------------- phase 0: staging ----------------
    {
        const float4* g4 = (const float4*)sh;  // 1024 float4 = 4096 floats
#pragma unroll
        for (int i = 0; i < 4; ++i) {
            int idx = tid + (i << 8);
            float4 v = g4[idx];
            int e = idx << 2;
            int row = e >> 6, col = e & 63;
            Sraw[row][col + 0] = v.x;
            Sraw[row][col + 1] = v.y;
            Sraw[row][col + 2] = v.z;
            Sraw[row][col + 3] = v.w;
        }
        if (tid < 80) {                        // 80 float4 = 320 floats
            int g0 = t0 - 32 + (tid << 2);
            float4 v;
            if (g0 >= 0 && g0 + 3 < T_LEN) {
                v = *(const float4*)(x + (size_t)b * T_LEN + g0);
            } else {
                float* vp = (float*)&v;
#pragma unroll
                for (int e = 0; e < 4; ++e) {
                    int g = g0 + e;
                    vp[e] = ((unsigned)g < (unsigned)T_LEN) ? x[(size_t)b * T_LEN + g] : 0.f;
                }
            }
            *(float4*)&xs[tid << 2] = v;
        }
    }
    __syncthreads();

    // ---------------- phase 1: in-block prep ----------------
    if (tid < 64) {
        // One thread per shapelet: EXACT prior-round prep arithmetic (serial).
        const int p = tid;
        const int c = ((p & 3) << 4) + (p >> 2);   // permuted B row
        float s1 = 0.f;
        for (int l = 0; l < 64; ++l) s1 += Sraw[p][l];
        float mu = s1 * (1.f / 64.f);
        float sq = 0.f;
        for (int l = 0; l < 64; ++l) { float d = Sraw[p][l] - mu; sq = fmaf(d, d, sq); }
        float sd  = fmaxf(sqrtf(sq * (1.f / 64.f)), EPSF);
        float inv = 1.f / sd;
        float ssum = 0.f, ss2 = 0.f;
        for (int l2 = 0; l2 < 32; ++l2) {
            unsigned pk_h, pk_l;
            {   // element 2*l2 (low half)
                float v = Sraw[p][2 * l2];
                float s = (v - mu) * inv;
                unsigned ub = __float_as_uint(s);
                float hi = __uint_as_float(ub & 0xFFFF0000u);
                float lo = s - hi;
                unsigned lb = __float_as_uint(lo) & 0xFFFF0000u;
                pk_h = ub >> 16;
                pk_l = lb >> 16;
                float eff = hi + __uint_as_float(lb);
                ssum += eff;
                ss2  = fmaf(eff, eff, ss2);
            }
            {   // element 2*l2+1 (high half)
                float v = Sraw[p][2 * l2 + 1];
                float s = (v - mu) * inv;
                unsigned ub = __float_as_uint(s);
                float hi = __uint_as_float(ub & 0xFFFF0000u);
                float lo = s - hi;
                unsigned lb = __float_as_uint(lo) & 0xFFFF0000u;
                pk_h |= (ub & 0xFFFF0000u);
                pk_l |= lb;
                float eff = hi + __uint_as_float(lb);
                ssum += eff;
                ss2  = fmaf(eff, eff, ss2);
            }
            *(unsigned*)&Bhi[c][2 * l2] = pk_h;
            *(unsigned*)&Blo[c][2 * l2] = pk_l;
        }
        lsum[p] = ssum;
        ls2[p]  = ss2;
    } else {
        // per-row window stats (verbatim math); threads 64-255 -> rows 0-191,
        // threads 64-127 additionally rows 192-255.
        int r = tid - 64;
#pragma unroll
        for (int pass = 0; pass < 2; ++pass) {
            if (pass == 0 || r < 64 + 192) {   // second pass only for tid<128
                float s1 = 0.f, sq = 0.f;
#pragma unroll
                for (int l = 0; l < 64; ++l) {
                    float v = xs[r + l];
                    s1 += v; sq = fmaf(v, v, sq);
                }
                float mu  = s1 * (1.f / 64.f);
                float var = fmaxf(sq * (1.f / 64.f) - mu * mu, 0.f);
                float sd  = fmaxf(sqrtf(var), EPSF);
                float inv = 1.f / sd;
                lmu[r]  = mu;
                linv[r] = inv;
                lw2[r]  = 64.f * var * inv * inv;
            }
            if (tid >= 128) break;
            r = tid - 64 + 192;                // rows 192..255
            if (pass == 1) break;
        }
    }
    __syncthreads();

    // ---------------- phase 1.5: pre-pack x window to bf16 hi/lo pairs ------
    // Sraw is dead now; alias its first 1280 B. xpack[i]     = shorts(2i,2i+1) hi
    //                                           xpack[160+i] = shorts(2i,2i+1) lo
    // Element arithmetic is bit-identical to the old per-thread A-pack:
    //   hi = ub>>16 ; lo_short = float_as_uint(v - as_float(ub&0xFFFF0000))>>16
    unsigned* xpack = (unsigned*)&Sraw[0][0];
    if (tid < 160) {
        float2 vv = *(const float2*)&xs[tid << 1];
        unsigned u0 = __float_as_uint(vv.x);
        unsigned u1 = __float_as_uint(vv.y);
        float l0 = vv.x - __uint_as_float(u0 & 0xFFFF0000u);
        float l1 = vv.y - __uint_as_float(u1 & 0xFFFF0000u);
        // dst = { u0.b2, u0.b3, u1.b2, u1.b3 }  (low short first)
        xpack[tid]       = __builtin_amdgcn_perm(u1, u0, 0x07060302u);
        xpack[160 + tid] = __builtin_amdgcn_perm(__float_as_uint(l1),
                                                 __float_as_uint(l0), 0x07060302u);
    }
    __syncthreads();

    // ---------------- phase 2: MFMA main ----------------
    // B-operand layout: lane holds B[k = quad*8+j + 32*h][col = lane&15];
    // permuted B row c = pt*16+n is logical shapelet 4n+pt.
    short8 Bh[4][2], Bl[4][2];
#pragma unroll
    for (int pt = 0; pt < 4; ++pt)
#pragma unroll
        for (int h = 0; h < 2; ++h) {
            Bh[pt][h] = *(const short8*)&Bhi[pt * 16 + n][h * 32 + (quad << 3)];
            Bl[pt][h] = *(const short8*)&Blo[pt * 16 + n][h * 32 + (quad << 3)];
        }
    const float4 sm4 = *(const float4*)&lsum[n << 2];   // logical 4n..4n+3
    const float4 sv4 = *(const float4*)&ls2[n << 2];

    const unsigned bsh = (unsigned)((n & 1) << 1);      // byte shift 0 or 2

#pragma unroll
    for (int u = 0; u < 4; ++u) {
        // A fragments: A[m][k] = xs[u*64 + wave*16 + m + k], prepacked bf16.
        // Lane needs shorts [sbase + 32h, +8) of hi and lo streams; dword base
        // sbase>>1, odd-short offsets resolved by v_alignbyte_b32.
        const int sbase = (u << 6) + (wave << 4) + n + (quad << 3);
        const unsigned* bp = xpack + (sbase >> 1);
        unsigned Dh0[5], Dh1[5], Dl0[5], Dl1[5];
#pragma unroll
        for (int k = 0; k < 5; ++k) {
            Dh0[k] = bp[k];            // hi, h=0
            Dh1[k] = bp[16 + k];       // hi, h=1 (+32 shorts)
            Dl0[k] = bp[160 + k];      // lo, h=0
            Dl1[k] = bp[176 + k];      // lo, h=1
        }
        union { unsigned w[4]; short8 v; } ah0, ah1, al0, al1;
#pragma unroll
        for (int k = 0; k < 4; ++k) {
            ah0.w[k] = __builtin_amdgcn_alignbyte(Dh0[k + 1], Dh0[k], bsh);
            ah1.w[k] = __builtin_amdgcn_alignbyte(Dh1[k + 1], Dh1[k], bsh);
            al0.w[k] = __builtin_amdgcn_alignbyte(Dl0[k + 1], Dl0[k], bsh);
            al1.w[k] = __builtin_amdgcn_alignbyte(Dl1[k + 1], Dl1[k], bsh);
        }
        short8 Ah[2] = { ah0.v, ah1.v };
        short8 Al[2] = { al0.v, al1.v };

        float4v acc[4];
#pragma unroll
        for (int pt = 0; pt < 4; ++pt) {
            float4v a = {0.f, 0.f, 0.f, 0.f};
#pragma unroll
            for (int h = 0; h < 2; ++h) {
                a = __builtin_amdgcn_mfma_f32_16x16x32_bf16(Ah[h], Bh[pt][h], a, 0, 0, 0);
                a = __builtin_amdgcn_mfma_f32_16x16x32_bf16(Ah[h], Bl[pt][h], a, 0, 0, 0);
                a = __builtin_amdgcn_mfma_f32_16x16x32_bf16(Al[h], Bh[pt][h], a, 0, 0, 0);
            }
            acc[pt] = a;
        }

        // epilogue: fold window znorm + exp, float4 store at cols 4n..4n+3
#pragma unroll
        for (int r = 0; r < 4; ++r) {
            // C/D layout: col = lane&15, row = quad*4 + r
            int tl = (u << 6) + (wave << 4) + (quad << 2) + r;
            int tg = t0 + tl;
            bool valid = (tg >= 32) && (tg <= 8160);
            float mu  = lmu[tl];
            float inv = linv[tl];
            float w2  = lw2[tl];
            float d0 = (acc[0][r] - mu * sm4.x) * inv;
            float d1 = (acc[1][r] - mu * sm4.y) * inv;
            float d2 = (acc[2][r] - mu * sm4.z) * inv;
            float d3 = (acc[3][r] - mu * sm4.w) * inv;
            float4 o;
            o.x = valid ? __expf(-(w2 + sv4.x - 2.f * d0)) : 0.f;
            o.y = valid ? __expf(-(w2 + sv4.y - 2.f * d1)) : 0.f;
            o.z = valid ? __expf(-(w2 + sv4.z - 2.f * d2)) : 0.f;
            o.w = valid ? __expf(-(w2 + sv4.w - 2.f * d3)) : 0.f;
            *(float4*)(out + (((size_t)(b * T_LEN + tg)) << 6) + (n << 2)) = o;
        }
    }
}

extern "C" void kernel_launch(void* const* d_in, const int* in_sizes, int n_in,
                              void* d_out, int out_size, void* d_ws, size_t ws_size,
                              hipStream_t stream) {
    const float* x  = (const float*)d_in[0];   // (32, 8192, 1)
    const float* sh = (const float*)d_in[1];   // (64, 1, 64)
    float* out = (float*)d_out;                // (32, 8192, 64)

    shapelet_fused<<<32 * 32, 256, 0, stream>>>(x, sh, out);
}

// Round 2
// 87.243 us; speedup vs baseline: 1.0045x; 1.0045x over previous
//
#include <hip/hip_runtime.h>
#include <math.h>

#define T_LEN 8192
#define EPSF  1e-6f

typedef __attribute__((ext_vector_type(8))) short short8;
typedef __attribute__((ext_vector_type(4))) float float4v;

// ---------------------------------------------------------------------------
// Two dispatches.
//
// Kernel 1 (shapelet_prep, 1 block x 64 threads): the EXACT per-shapelet
//   two-pass znorm + bf16 hi/lo split from prior rounds (bit-identical
//   arithmetic, same accumulation order), computed ONCE instead of once per
//   block, written to d_ws:
//     ws[0      ..  8191]  Bhi_g : 64 rows x 64 shorts, permuted row c
//     ws[8192   .. 16383]  Blo_g
//     ws[16384  .. 16639]  lsum_g: 64 floats (logical-p order)
//     ws[16640  .. 16895]  ls2_g
//
// Kernel 2 (shapelet_main, 1024 blocks x 256, __launch_bounds__(256,4)):
//   one block = (batch b, 256-row t-strip). B fragments + shapelet stats are
//   loaded DIRECTLY from global into registers at kernel start (L2-broadcast;
//   latency hidden under xs staging + window stats). No Sraw/Bhi/Blo in LDS:
//   LDS = xs(1.25K) + lstat(4K) ~= 5.4 KB (was 39.9 KB). Barriers 3 -> 2.
//   Window stats: one row per thread (all 256), verbatim math, packed as
//   float4 {mu, inv, w2} so the epilogue reads one b128 per row.
//   Phase-2 body (A-pack, 3-MFMA hi/lo GEMM, epilogue) is verbatim the
//   proven 82.9us version. Rows t<32 / t>8160 are the reference's zero pad.
// ---------------------------------------------------------------------------

__global__ __launch_bounds__(64, 1) void shapelet_prep(
        const float* __restrict__ sh, void* __restrict__ ws) {
    unsigned short* Bhi_g = (unsigned short*)ws;
    unsigned short* Blo_g = Bhi_g + 64 * 64;
    float* lsum_g = (float*)((char*)ws + 16384);
    float* ls2_g  = lsum_g + 64;

    const int p = threadIdx.x;
    const int c = ((p & 3) << 4) + (p >> 2);   // permuted B row

    // load shapelet p into registers (16 x dwordx4, coalesced per-lane 16B)
    float S[64];
    const float4* s4 = (const float4*)(sh + (size_t)p * 64);
#pragma unroll
    for (int i = 0; i < 16; ++i) {
        float4 v = s4[i];
        S[4 * i + 0] = v.x;
        S[4 * i + 1] = v.y;
        S[4 * i + 2] = v.z;
        S[4 * i + 3] = v.w;
    }

    // EXACT prior-round prep arithmetic (same order, same ops).
    float s1 = 0.f;
#pragma unroll
    for (int l = 0; l < 64; ++l) s1 += S[l];
    float mu = s1 * (1.f / 64.f);
    float sq = 0.f;
#pragma unroll
    for (int l = 0; l < 64; ++l) { float d = S[l] - mu; sq = fmaf(d, d, sq); }
    float sd  = fmaxf(sqrtf(sq * (1.f / 64.f)), EPSF);
    float inv = 1.f / sd;
    float ssum = 0.f, ss2 = 0.f;
#pragma unroll
    for (int l2 = 0; l2 < 32; ++l2) {
        unsigned pk_h, pk_l;
        {   // element 2*l2 (low half)
            float v = S[2 * l2];
            float s = (v - mu) * inv;
            unsigned ub = __float_as_uint(s);
            float hi = __uint_as_float(ub & 0xFFFF0000u);
            float lo = s - hi;
            unsigned lb = __float_as_uint(lo) & 0xFFFF0000u;
            pk_h = ub >> 16;
            pk_l = lb >> 16;
            float eff = hi + __uint_as_float(lb);
            ssum += eff;
            ss2  = fmaf(eff, eff, ss2);
        }
        {   // element 2*l2+1 (high half)
            float v = S[2 * l2 + 1];
            float s = (v - mu) * inv;
            unsigned ub = __float_as_uint(s);
            float hi = __uint_as_float(ub & 0xFFFF0000u);
            float lo = s - hi;
            unsigned lb = __float_as_uint(lo) & 0xFFFF0000u;
            pk_h |= (ub & 0xFFFF0000u);
            pk_l |= lb;
            float eff = hi + __uint_as_float(lb);
            ssum += eff;
            ss2  = fmaf(eff, eff, ss2);
        }
        *(unsigned*)&Bhi_g[c * 64 + 2 * l2] = pk_h;
        *(unsigned*)&Blo_g[c * 64 + 2 * l2] = pk_l;
    }
    lsum_g[p] = ssum;
    ls2_g[p]  = ss2;
}

__global__ __launch_bounds__(256, 4) void shapelet_main(
        const float* __restrict__ x,
        const void* __restrict__ ws,
        float* __restrict__ out) {
    __shared__ __align__(16) float xs[320];      // x[t0-32 .. t0+287]
    __shared__ float4 lstat[256];                // {mu, inv, w2, -} per row

    const int tid  = threadIdx.x;
    const int lane = tid & 63;
    const int wave = tid >> 6;
    const int n    = lane & 15;
    const int quad = lane >> 4;

    const int super = blockIdx.x & 31;           // 32 strips of 256 rows
    const int b     = blockIdx.x >> 5;           // 32 batches
    const int t0    = super << 8;

    const unsigned short* Bhi_g = (const unsigned short*)ws;
    const unsigned short* Blo_g = Bhi_g + 64 * 64;
    const float* lsum_g = (const float*)((const char*)ws + 16384);

    // ---- issue B-fragment + stat loads early (L2-broadcast); latency hides
    // under xs staging + window stats. Layout matches prior LDS fragments:
    // lane holds B[k = quad*8+j + 32*h][col = lane&15]; permuted row
    // c = pt*16+n is logical shapelet 4n+pt.
    short8 Bh[4][2], Bl[4][2];
#pragma unroll
    for (int pt = 0; pt < 4; ++pt)
#pragma unroll
        for (int h = 0; h < 2; ++h) {
            int off = ((pt * 16 + n) << 6) + (h << 5) + (quad << 3);
            Bh[pt][h] = *(const short8*)(Bhi_g + off);
            Bl[pt][h] = *(const short8*)(Blo_g + off);
        }
    const float4 sm4 = *(const float4*)(lsum_g + (n << 2));        // logical 4n..4n+3
    const float4 sv4 = *(const float4*)(lsum_g + 64 + (n << 2));

    // ---- stage x window into LDS (80 float4 = 320 floats)
    if (tid < 80) {
        int g0 = t0 - 32 + (tid << 2);
        float4 v;
        if (g0 >= 0 && g0 + 3 < T_LEN) {
            v = *(const float4*)(x + (size_t)b * T_LEN + g0);
        } else {
            float* vp = (float*)&v;
#pragma unroll
            for (int e = 0; e < 4; ++e) {
                int g = g0 + e;
                vp[e] = ((unsigned)g < (unsigned)T_LEN) ? x[(size_t)b * T_LEN + g] : 0.f;
            }
        }
        *(float4*)&xs[tid << 2] = v;
    }
    __syncthreads();

    // ---- window stats: one row per thread, verbatim math
    {
        const int r = tid;
        float s1 = 0.f, sq = 0.f;
#pragma unroll
        for (int l = 0; l < 64; ++l) {
            float v = xs[r + l];
            s1 += v; sq = fmaf(v, v, sq);
        }
        float mu  = s1 * (1.f / 64.f);
        float var = fmaxf(sq * (1.f / 64.f) - mu * mu, 0.f);
        float sd  = fmaxf(sqrtf(var), EPSF);
        float inv = 1.f / sd;
        float4 st;
        st.x = mu;
        st.y = inv;
        st.z = 64.f * var * inv * inv;
        st.w = 0.f;
        lstat[r] = st;
    }
    __syncthreads();

    // ---- phase 2: MFMA main (verbatim proven body)
#pragma unroll
    for (int u = 0; u < 4; ++u) {
        // A fragments: A[m][k] = xs[u*64 + wave*16 + m + k]
        const int abase = (u << 6) + (wave << 4) + n + (quad << 3);
        short8 Ah[2], Al[2];
#pragma unroll
        for (int h = 0; h < 2; ++h) {
#pragma unroll
            for (int j = 0; j < 8; ++j) {
                float v = xs[abase + h * 32 + j];
                unsigned ub = __float_as_uint(v);
                unsigned hb = ub & 0xFFFF0000u;
                float lo = v - __uint_as_float(hb);
                Ah[h][j] = (short)(ub >> 16);
                Al[h][j] = (short)(__float_as_uint(lo) >> 16);
            }
        }

        float4v acc[4];
#pragma unroll
        for (int pt = 0; pt < 4; ++pt) {
            float4v a = {0.f, 0.f, 0.f, 0.f};
#pragma unroll
            for (int h = 0; h < 2; ++h) {
                a = __builtin_amdgcn_mfma_f32_16x16x32_bf16(Ah[h], Bh[pt][h], a, 0, 0, 0);
                a = __builtin_amdgcn_mfma_f32_16x16x32_bf16(Ah[h], Bl[pt][h], a, 0, 0, 0);
                a = __builtin_amdgcn_mfma_f32_16x16x32_bf16(Al[h], Bh[pt][h], a, 0, 0, 0);
            }
            acc[pt] = a;
        }

        // epilogue: fold window znorm + exp, float4 store at cols 4n..4n+3
#pragma unroll
        for (int r = 0; r < 4; ++r) {
            // C/D layout: col = lane&15, row = quad*4 + r
            int tl = (u << 6) + (wave << 4) + (quad << 2) + r;
            int tg = t0 + tl;
            bool valid = (tg >= 32) && (tg <= 8160);
            float4 st = lstat[tl];
            float mu  = st.x;
            float inv = st.y;
            float w2  = st.z;
            float d0 = (acc[0][r] - mu * sm4.x) * inv;
            float d1 = (acc[1][r] - mu * sm4.y) * inv;
            float d2 = (acc[2][r] - mu * sm4.z) * inv;
            float d3 = (acc[3][r] - mu * sm4.w) * inv;
            float4 o;
            o.x = valid ? __expf(-(w2 + sv4.x - 2.f * d0)) : 0.f;
            o.y = valid ? __expf(-(w2 + sv4.y - 2.f * d1)) : 0.f;
            o.z = valid ? __expf(-(w2 + sv4.z - 2.f * d2)) : 0.f;
            o.w = valid ? __expf(-(w2 + sv4.w - 2.f * d3)) : 0.f;
            *(float4*)(out + (((size_t)(b * T_LEN + tg)) << 6) + (n << 2)) = o;
        }
    }
}

extern "C" void kernel_launch(void* const* d_in, const int* in_sizes, int n_in,
                              void* d_out, int out_size, void* d_ws, size_t ws_size,
                              hipStream_t stream) {
    const float* x  = (const float*)d_in[0];   // (32, 8192, 1)
    const float* sh = (const float*)d_in[1];   // (64, 1, 64)
    float* out = (float*)d_out;                // (32, 8192, 64)

    shapelet_prep<<<1, 64, 0, stream>>>(sh, d_ws);
    shapelet_main<<<32 * 32, 256, 0, stream>>>(x, d_ws, out);
}

// Round 3
// 83.331 us; speedup vs baseline: 1.0517x; 1.0469x over previous
//
#include <hip/hip_runtime.h>
#include <math.h>

#define T_LEN 8192
#define EPSF  1e-6f

typedef __attribute__((ext_vector_type(8))) short short8;
typedef __attribute__((ext_vector_type(4))) float float4v;

// ---------------------------------------------------------------------------
// Single fused kernel (one dispatch — the R2 prep-kernel split cost ~4 µs in
// dispatch overhead + cold-start B broadcast and is reverted).
// One block = (batch b, 256-row t-strip), 1024 blocks x 256 threads,
// __launch_bounds__(256,4): exactly 4 blocks/CU, one residency round.
//
// Phase 0/1 (merged, one barrier):
//   threads 0-63 : load own shapelet GLOBAL->registers (16 x dwordx4; no
//                  Sraw LDS staging at all), then the EXACT serial two-pass
//                  znorm + bf16 hi/lo split of prior rounds (bit-identical
//                  arithmetic, same order), written to LDS Bhi/Blo at
//                  permuted row c = (p&3)*16 + (p>>2), plus lsum/ls2.
//   threads 64-143: stage x window (80 float4 -> xs[320]).
//   barrier.
// Phase 1.5: window stats, one row per thread (all 256), verbatim math,
//   packed as float4 {mu, inv, w2} -> lstat so the epilogue reads ONE b128
//   per row (was 3 scalar b32). B fragments + shapelet stats -> registers.
//   barrier.
// Phase 2: verbatim proven MFMA body: per u (four 64-row units) A-pack from
//   xs, 3-MFMA bf16 hi/lo GEMM (Ah*Bh + Ah*Bl + Al*Bh), epilogue folds
//   window znorm + exp, float4 stores (lane n owns cols 4n..4n+3).
//   Rows t<32 / t>8160 are the reference's zero padding.
// LDS: Bhi/Blo 18 KB + xs 1.25 KB + lstat 4 KB + lsum/ls2 0.5 KB ~= 23.8 KB.
// ---------------------------------------------------------------------------
__global__ __launch_bounds__(256, 4) void shapelet_fused(
        const float* __restrict__ x,
        const float* __restrict__ sh,
        float* __restrict__ out) {
    __shared__ unsigned short Bhi[64][72];     // 9 KB, 144 B rows (16B-aligned)
    __shared__ unsigned short Blo[64][72];     // 9 KB
    __shared__ __align__(16) float xs[320];    // x[t0-32 .. t0+287]
    __shared__ float4 lstat[256];              // {mu, inv, w2, -} per row
    __shared__ __align__(16) float lsum[64];   // logical-p order
    __shared__ __align__(16) float ls2[64];

    const int tid  = threadIdx.x;
    const int lane = tid & 63;
    const int wave = tid >> 6;
    const int n    = lane & 15;
    const int quad = lane >> 4;

    const int super = blockIdx.x & 31;         // 32 strips of 256 rows
    const int b     = blockIdx.x >> 5;         // 32 batches
    const int t0    = super << 8;

    // ---------------- phase 0/1: prep (global->reg) + xs staging ----------
    if (tid < 64) {
        const int p = tid;
        const int c = ((p & 3) << 4) + (p >> 2);   // permuted B row

        // load shapelet p into registers (16 x dwordx4)
        float S[64];
        const float4* s4 = (const float4*)(sh + (size_t)p * 64);
#pragma unroll
        for (int i = 0; i < 16; ++i) {
            float4 v = s4[i];
            S[4 * i + 0] = v.x;
            S[4 * i + 1] = v.y;
            S[4 * i + 2] = v.z;
            S[4 * i + 3] = v.w;
        }

        // EXACT prior-round prep arithmetic (same order, same ops).
        float s1 = 0.f;
#pragma unroll
        for (int l = 0; l < 64; ++l) s1 += S[l];
        float mu = s1 * (1.f / 64.f);
        float sq = 0.f;
#pragma unroll
        for (int l = 0; l < 64; ++l) { float d = S[l] - mu; sq = fmaf(d, d, sq); }
        float sd  = fmaxf(sqrtf(sq * (1.f / 64.f)), EPSF);
        float inv = 1.f / sd;
        float ssum = 0.f, ss2 = 0.f;
#pragma unroll
        for (int l2 = 0; l2 < 32; ++l2) {
            unsigned pk_h, pk_l;
            {   // element 2*l2 (low half)
                float v = S[2 * l2];
                float s = (v - mu) * inv;
                unsigned ub = __float_as_uint(s);
                float hi = __uint_as_float(ub & 0xFFFF0000u);
                float lo = s - hi;
                unsigned lb = __float_as_uint(lo) & 0xFFFF0000u;
                pk_h = ub >> 16;
                pk_l = lb >> 16;
                float eff = hi + __uint_as_float(lb);
                ssum += eff;
                ss2  = fmaf(eff, eff, ss2);
            }
            {   // element 2*l2+1 (high half)
                float v = S[2 * l2 + 1];
                float s = (v - mu) * inv;
                unsigned ub = __float_as_uint(s);
                float hi = __uint_as_float(ub & 0xFFFF0000u);
                float lo = s - hi;
                unsigned lb = __float_as_uint(lo) & 0xFFFF0000u;
                pk_h |= (ub & 0xFFFF0000u);
                pk_l |= lb;
                float eff = hi + __uint_as_float(lb);
                ssum += eff;
                ss2  = fmaf(eff, eff, ss2);
            }
            *(unsigned*)&Bhi[c][2 * l2] = pk_h;
            *(unsigned*)&Blo[c][2 * l2] = pk_l;
        }
        lsum[p] = ssum;
        ls2[p]  = ss2;
    } else if (tid < 144) {
        // stage x window into LDS (80 float4 = 320 floats)
        const int i = tid - 64;
        int g0 = t0 - 32 + (i << 2);
        float4 v;
        if (g0 >= 0 && g0 + 3 < T_LEN) {
            v = *(const float4*)(x + (size_t)b * T_LEN + g0);
        } else {
            float* vp = (float*)&v;
#pragma unroll
            for (int e = 0; e < 4; ++e) {
                int g = g0 + e;
                vp[e] = ((unsigned)g < (unsigned)T_LEN) ? x[(size_t)b * T_LEN + g] : 0.f;
            }
        }
        *(float4*)&xs[i << 2] = v;
    }
    __syncthreads();

    // ---------------- phase 1.5: window stats + fragment loads -------------
    {
        const int r = tid;
        float s1 = 0.f, sq = 0.f;
#pragma unroll
        for (int l = 0; l < 64; ++l) {
            float v = xs[r + l];
            s1 += v; sq = fmaf(v, v, sq);
        }
        float mu  = s1 * (1.f / 64.f);
        float var = fmaxf(sq * (1.f / 64.f) - mu * mu, 0.f);
        float sd  = fmaxf(sqrtf(var), EPSF);
        float inv = 1.f / sd;
        float4 st;
        st.x = mu;
        st.y = inv;
        st.z = 64.f * var * inv * inv;
        st.w = 0.f;
        lstat[r] = st;
    }

    // B fragments -> registers (layout identical to proven kernel):
    // lane holds B[k = quad*8+j + 32*h][col = lane&15]; permuted row
    // c = pt*16+n is logical shapelet 4n+pt.
    short8 Bh[4][2], Bl[4][2];
#pragma unroll
    for (int pt = 0; pt < 4; ++pt)
#pragma unroll
        for (int h = 0; h < 2; ++h) {
            Bh[pt][h] = *(const short8*)&Bhi[pt * 16 + n][h * 32 + (quad << 3)];
            Bl[pt][h] = *(const short8*)&Blo[pt * 16 + n][h * 32 + (quad << 3)];
        }
    const float4 sm4 = *(const float4*)&lsum[n << 2];   // logical 4n..4n+3
    const float4 sv4 = *(const float4*)&ls2[n << 2];
    __syncthreads();

    // ---------------- phase 2: MFMA main (verbatim proven body) ------------
#pragma unroll
    for (int u = 0; u < 4; ++u) {
        // A fragments: A[m][k] = xs[u*64 + wave*16 + m + k]
        const int abase = (u << 6) + (wave << 4) + n + (quad << 3);
        short8 Ah[2], Al[2];
#pragma unroll
        for (int h = 0; h < 2; ++h) {
#pragma unroll
            for (int j = 0; j < 8; ++j) {
                float v = xs[abase + h * 32 + j];
                unsigned ub = __float_as_uint(v);
                unsigned hb = ub & 0xFFFF0000u;
                float lo = v - __uint_as_float(hb);
                Ah[h][j] = (short)(ub >> 16);
                Al[h][j] = (short)(__float_as_uint(lo) >> 16);
            }
        }

        float4v acc[4];
#pragma unroll
        for (int pt = 0; pt < 4; ++pt) {
            float4v a = {0.f, 0.f, 0.f, 0.f};
#pragma unroll
            for (int h = 0; h < 2; ++h) {
                a = __builtin_amdgcn_mfma_f32_16x16x32_bf16(Ah[h], Bh[pt][h], a, 0, 0, 0);
                a = __builtin_amdgcn_mfma_f32_16x16x32_bf16(Ah[h], Bl[pt][h], a, 0, 0, 0);
                a = __builtin_amdgcn_mfma_f32_16x16x32_bf16(Al[h], Bh[pt][h], a, 0, 0, 0);
            }
            acc[pt] = a;
        }

        // epilogue: fold window znorm + exp, float4 store at cols 4n..4n+3
#pragma unroll
        for (int r = 0; r < 4; ++r) {
            // C/D layout: col = lane&15, row = quad*4 + r
            int tl = (u << 6) + (wave << 4) + (quad << 2) + r;
            int tg = t0 + tl;
            bool valid = (tg >= 32) && (tg <= 8160);
            float4 st = lstat[tl];
            float mu  = st.x;
            float inv = st.y;
            float w2  = st.z;
            float d0 = (acc[0][r] - mu * sm4.x) * inv;
            float d1 = (acc[1][r] - mu * sm4.y) * inv;
            float d2 = (acc[2][r] - mu * sm4.z) * inv;
            float d3 = (acc[3][r] - mu * sm4.w) * inv;
            float4 o;
            o.x = valid ? __expf(-(w2 + sv4.x - 2.f * d0)) : 0.f;
            o.y = valid ? __expf(-(w2 + sv4.y - 2.f * d1)) : 0.f;
            o.z = valid ? __expf(-(w2 + sv4.z - 2.f * d2)) : 0.f;
            o.w = valid ? __expf(-(w2 + sv4.w - 2.f * d3)) : 0.f;
            *(float4*)(out + (((size_t)(b * T_LEN + tg)) << 6) + (n << 2)) = o;
        }
    }
}

extern "C" void kernel_launch(void* const* d_in, const int* in_sizes, int n_in,
                              void* d_out, int out_size, void* d_ws, size_t ws_size,
                              hipStream_t stream) {
    const float* x  = (const float*)d_in[0];   // (32, 8192, 1)
    const float* sh = (const float*)d_in[1];   // (64, 1, 64)
    float* out = (float*)d_out;                // (32, 8192, 64)

    shapelet_fused<<<32 * 32, 256, 0, stream>>>(x, sh, out);
}